// Round 5
// baseline (567.874 us; speedup 1.0000x reference)
//
#include <hip/hip_runtime.h>

typedef __bf16 bf16_t;
typedef bf16_t bf16x8 __attribute__((ext_vector_type(8)));
typedef bf16_t bf16x4 __attribute__((ext_vector_type(4)));
typedef float f32x4 __attribute__((ext_vector_type(4)));
typedef float f32x16 __attribute__((ext_vector_type(16)));

#define BATCH 4
#define SEQ 4096
#define EMBED 512
#define MTOT (BATCH * SEQ)
#define NSPLIT 4
#define KT (SEQ / NSPLIT)     // 1024 keys per block
#define BC 64
#define FITERS (KT / BC)      // 16

__device__ float  Lacc_g[MTOT];         // row sum-of-exp accumulator
__device__ bf16_t Wbf_g[EMBED * EMBED]; // W pre-converted to bf16

// ---------------------------------------------------------------------------
// Stage 0: W fp32 -> bf16 once
// ---------------------------------------------------------------------------
__global__ __launch_bounds__(256) void cvt_w_kernel(const float* __restrict__ W) {
    const int i = (blockIdx.x * 256 + threadIdx.x) * 4;
    float4 v = *(const float4*)&W[i];
    bf16x4 o;
    o[0] = (bf16_t)v.x; o[1] = (bf16_t)v.y; o[2] = (bf16_t)v.z; o[3] = (bf16_t)v.w;
    *(bf16x4*)&Wbf_g[i] = o;
}

// ---------------------------------------------------------------------------
// Stage 1: q = cos(x + theta) @ W^T + b  (M=16384, N=512, K=512).
// m-tile 32, full n=512 per block, grid 512. Writes qrow + per-batch
// transpose qt. Also zeroes Lacc_g.
// ---------------------------------------------------------------------------
__global__ __launch_bounds__(256, 2) void gemm_q_kernel(
    const float* __restrict__ x, const float* __restrict__ theta,
    const float* __restrict__ bias,
    bf16_t* __restrict__ qrow, bf16_t* __restrict__ qt)
{
    __shared__ alignas(16) bf16_t As[32][40];
    __shared__ alignas(16) bf16_t Ws[512][40];
    __shared__ float th[64];

    const int t    = threadIdx.x;
    const int m0   = blockIdx.x * 32;
    const int lane = t & 63;
    const int wave = t >> 6;
    const int l15  = lane & 15;
    const int quad = lane >> 4;

    if (t < 64) th[t] = theta[t];
    if (blockIdx.x < 16)
        ((float4*)Lacc_g)[blockIdx.x * 256 + t] = make_float4(0.f, 0.f, 0.f, 0.f);

    f32x4 acc[2][8];
#pragma unroll
    for (int m = 0; m < 2; ++m)
#pragma unroll
        for (int n = 0; n < 8; ++n) acc[m][n] = (f32x4){0.f, 0.f, 0.f, 0.f};

    const int arow = t >> 3;          // 0..31
    const int aseg = t & 7;           // 0..7 (4 floats)

    for (int kk = 0; kk < 16; ++kk) {
        const int k0 = kk * 32;
        __syncthreads();
        {   // A = bf16(cos(x+theta)): 32 x 32
            float4 xv = *(const float4*)&x[(m0 + arow) * 512 + k0 + aseg * 4];
            bf16x4 av;
            av[0] = (bf16_t)__cosf(xv.x + th[(k0 + aseg * 4 + 0) & 63]);
            av[1] = (bf16_t)__cosf(xv.y + th[(k0 + aseg * 4 + 1) & 63]);
            av[2] = (bf16_t)__cosf(xv.z + th[(k0 + aseg * 4 + 2) & 63]);
            av[3] = (bf16_t)__cosf(xv.w + th[(k0 + aseg * 4 + 3) & 63]);
            *(bf16x4*)&As[arow][aseg * 4] = av;
        }
        // W (already bf16): 512 rows x 32 k
#pragma unroll
        for (int cc = 0; cc < 8; ++cc) {
            int idx = t + 256 * cc;       // 0..2047
            int row = idx >> 2;           // 0..511
            int seg = idx & 3;            // 8 shorts each
            *(bf16x8*)&Ws[row][seg * 8] =
                *(const bf16x8*)&Wbf_g[row * 512 + k0 + seg * 8];
        }
        __syncthreads();
        bf16x8 af[2];
#pragma unroll
        for (int m = 0; m < 2; ++m)
            af[m] = *(const bf16x8*)&As[m * 16 + l15][quad * 8];
#pragma unroll
        for (int n = 0; n < 8; ++n) {
            bf16x8 bfr = *(const bf16x8*)&Ws[wave * 128 + n * 16 + l15][quad * 8];
#pragma unroll
            for (int m = 0; m < 2; ++m)
                acc[m][n] = __builtin_amdgcn_mfma_f32_16x16x32_bf16(af[m], bfr, acc[m][n], 0, 0, 0);
        }
    }

#pragma unroll
    for (int n = 0; n < 8; ++n) {
        const int col = wave * 128 + n * 16 + l15;
        const float bv = bias[col];
#pragma unroll
        for (int m = 0; m < 2; ++m) {
            const int row0 = m0 + m * 16 + quad * 4;
            bf16x4 pack;
#pragma unroll
            for (int r = 0; r < 4; ++r) {
                bf16_t qv = (bf16_t)(acc[m][n][r] + bv);
                qrow[(row0 + r) * 512 + col] = qv;
                pack[r] = qv;
            }
            const int b  = row0 >> 12;
            const int i0 = row0 & 4095;
            *(bf16x4*)&qt[((size_t)(b * 512 + col) << 12) + i0] = pack;
        }
    }
}

// ---------------------------------------------------------------------------
// Stage 2: attention via 32x32x16 MFMA, S^T formulation (A=K, B=Q so the C/D
// layout packs P as b64 row-major writes, and PV A-frags are contiguous b128).
// Br=64, Bc=64, KV-split 4 -> grid 1024, 2 barriers per 64 keys.
// Q staged once in LDS; K/V fragments direct from global (L2-served).
// Unnormalized O atomicAdd'ed into out; exp-sums into Lacc_g.
// ---------------------------------------------------------------------------
__global__ __launch_bounds__(256, 2) void flash_kernel(
    const bf16_t* __restrict__ q, const bf16_t* __restrict__ qt,
    float* __restrict__ out)
{
    __shared__ alignas(16) bf16_t Qs[64][520];   // 66560 B, stride 260 dw (=4 mod 32)
    __shared__ alignas(16) bf16_t Ps[64][72];    // 9216 B,  stride 36 dw  (=4 mod 32)

    const int t    = threadIdx.x;
    const int lane = t & 63;
    const int wave = t >> 6;
    const int l31  = lane & 31;
    const int half = lane >> 5;

    // XCD-aware remap: each XCD's resident blocks share one (batch,ksplit)
    const int L      = blockIdx.x;            // 0..1023
    const int xcd    = L & 7;
    const int slot   = L >> 3;                // 0..127
    const int g      = xcd + 8 * (slot >> 6); // 0..15
    const int qtile  = slot & 63;
    const int batch  = g >> 2;
    const int ksplit = g & 3;

    const int q0    = qtile * 64;
    const int kbase = ksplit * KT;
    const bf16_t* qb  = q  + (size_t)batch * SEQ * EMBED;
    const bf16_t* qtb = qt + (size_t)batch * EMBED * SEQ;

    // stage Q tile [64 rows][512] into LDS (once)
#pragma unroll
    for (int i = 0; i < 16; ++i) {
        int c   = t + 256 * i;                // 0..4095
        int row = c >> 6;
        int seg = c & 63;
        *(bf16x8*)&Qs[row][seg * 8] = *(const bf16x8*)&qb[(size_t)(q0 + row) * 512 + seg * 8];
    }
    __syncthreads();

    const int kg = wave & 1;   // key-group (32 keys)
    const int rg = wave >> 1;  // q-row-group (32 rows)

    f32x16 O[2][4];            // [m-tile (q-rows)][n-tile (e)], e-range = wave*128
#pragma unroll
    for (int m = 0; m < 2; ++m)
#pragma unroll
        for (int n = 0; n < 4; ++n)
#pragma unroll
            for (int i = 0; i < 16; ++i) O[m][n][i] = 0.f;
    float lpart = 0.f;

    for (int it = 0; it < FITERS; ++it) {
        const int kq = kbase + it * BC + kg * 32;   // this wave's QK key base
        // ---- QK: S^T[32 keys][32 rows] = K * Q^T, K from global, Q from LDS
        f32x16 s;
#pragma unroll
        for (int i = 0; i < 16; ++i) s[i] = 0.f;
#pragma unroll
        for (int ks = 0; ks < 32; ++ks) {
            bf16x8 ak = *(const bf16x8*)&qb[(size_t)(kq + l31) * 512 + ks * 16 + half * 8];
            bf16x8 bq = *(const bf16x8*)&Qs[rg * 32 + l31][ks * 16 + half * 8];
            s = __builtin_amdgcn_mfma_f32_32x32x16_bf16(ak, bq, s, 0, 0, 0);
        }
        // ---- P = exp(s/8); C/D: col=l31=q-row, key = (reg&3)+8*(reg>>2)+4*half
        // pack reg-quads (4 consecutive keys) as b64 into Ps[q-row][key]
#pragma unroll
        for (int rq = 0; rq < 4; ++rq) {
            bf16x4 pk;
#pragma unroll
            for (int rr = 0; rr < 4; ++rr) {
                float p = __expf(s[rq * 4 + rr] * 0.125f);
                bf16_t pb = (bf16_t)p;
                lpart += (float)pb;
                pk[rr] = pb;
            }
            *(bf16x4*)&Ps[rg * 32 + l31][kg * 32 + rq * 8 + half * 4] = pk;
        }
        __syncthreads();   // B1: Ps(it) complete
        // ---- hoist PV A-frags (contiguous b128 from Ps)
        bf16x8 pa[2][4];   // [m-tile][k-step], k = kp*16 + half*8 + j
#pragma unroll
        for (int mt = 0; mt < 2; ++mt)
#pragma unroll
            for (int kp = 0; kp < 4; ++kp)
                pa[mt][kp] = *(const bf16x8*)&Ps[mt * 32 + l31][kp * 16 + half * 8];
        __syncthreads();   // B2: Ps reads done; next iter may overwrite
        // ---- PV: O += P * V, V-frags direct from global qt
        const int kv = kbase + it * BC;
#pragma unroll
        for (int nt = 0; nt < 4; ++nt) {
            const int e = wave * 128 + nt * 32 + l31;
#pragma unroll
            for (int kp = 0; kp < 4; ++kp) {
                bf16x8 bv = *(const bf16x8*)&qtb[(size_t)e * 4096 + kv + kp * 16 + half * 8];
#pragma unroll
                for (int mt = 0; mt < 2; ++mt)
                    O[mt][nt] = __builtin_amdgcn_mfma_f32_32x32x16_bf16(pa[mt][kp], bv, O[mt][nt], 0, 0, 0);
            }
        }
    }

    // ---- row exp-sums: lanes l and l+32 hold same q-row, different keys
    {
        float ls = lpart + __shfl_xor(lpart, 32);
        if (half == 0)
            atomicAdd(&Lacc_g[batch * SEQ + q0 + rg * 32 + l31], ls);
    }
    // ---- unnormalized O -> out; D: col=l31=e, row=(reg&3)+8*(reg>>2)+4*half
#pragma unroll
    for (int mt = 0; mt < 2; ++mt)
#pragma unroll
        for (int rq = 0; rq < 4; ++rq)
#pragma unroll
            for (int rr = 0; rr < 4; ++rr) {
                const int qr = mt * 32 + rq * 8 + half * 4 + rr;
                const size_t row = (size_t)batch * SEQ + q0 + qr;
#pragma unroll
                for (int nt = 0; nt < 4; ++nt)
                    atomicAdd(&out[row * 512 + wave * 128 + nt * 32 + l31],
                              O[mt][nt][rq * 4 + rr]);
            }
}

// out[row][e] /= Lacc_g[row]
__global__ __launch_bounds__(256) void norm_kernel(float* __restrict__ out)
{
    const int idx = blockIdx.x * 256 + threadIdx.x;   // float4 index
    float4 v = ((float4*)out)[idx];
    const float inv = 1.0f / Lacc_g[idx >> 7];
    v.x *= inv; v.y *= inv; v.z *= inv; v.w *= inv;
    ((float4*)out)[idx] = v;
}

extern "C" void kernel_launch(void* const* d_in, const int* in_sizes, int n_in,
                              void* d_out, int out_size, void* d_ws, size_t ws_size,
                              hipStream_t stream) {
    const float* x     = (const float*)d_in[0];
    const float* theta = (const float*)d_in[1];
    const float* W     = (const float*)d_in[2];
    const float* bias  = (const float*)d_in[3];
    float* out   = (float*)d_out;
    bf16_t* qrow = (bf16_t*)d_ws;                       // [16384][512] bf16
    bf16_t* qt   = qrow + (size_t)MTOT * EMBED;         // [4][512][4096] bf16

    hipMemsetAsync(out, 0, (size_t)MTOT * EMBED * sizeof(float), stream);

    cvt_w_kernel<<<dim3(EMBED * EMBED / 4 / 256), dim3(256), 0, stream>>>(W);

    gemm_q_kernel<<<dim3(MTOT / 32), dim3(256), 0, stream>>>(x, theta, bias, qrow, qt);

    flash_kernel<<<dim3(64 * BATCH * NSPLIT), dim3(256), 0, stream>>>(qrow, qt, out);

    norm_kernel<<<dim3(MTOT * EMBED / 4 / 256), dim3(256), 0, stream>>>(out);
}

// Round 6
// 437.103 us; speedup vs baseline: 1.2992x; 1.2992x over previous
//
#include <hip/hip_runtime.h>

typedef __bf16 bf16_t;
typedef bf16_t bf16x8 __attribute__((ext_vector_type(8)));
typedef bf16_t bf16x4 __attribute__((ext_vector_type(4)));
typedef float f32x4 __attribute__((ext_vector_type(4)));

#define BATCH 4
#define SEQ 4096
#define EMBED 512
#define MTOT (BATCH * SEQ)
#define NSPLIT 4
#define KT (SEQ / NSPLIT)     // 1024 keys per block
#define BC 32
#define FITERS (KT / BC)      // 32

__device__ float  Lacc_g[MTOT];         // row sum-of-exp accumulator
__device__ bf16_t Wbf_g[EMBED * EMBED]; // W pre-converted to bf16

// async global->LDS, 16 B per lane; lds base must be wave-uniform
__device__ __forceinline__ void async_copy16(const bf16_t* g, bf16_t* l) {
    __builtin_amdgcn_global_load_lds(
        (const __attribute__((address_space(1))) unsigned int*)g,
        (__attribute__((address_space(3))) unsigned int*)l, 16, 0, 0);
}

// ---------------------------------------------------------------------------
// Stage 0: W fp32 -> bf16 once
// ---------------------------------------------------------------------------
__global__ __launch_bounds__(256) void cvt_w_kernel(const float* __restrict__ W) {
    const int i = (blockIdx.x * 256 + threadIdx.x) * 4;
    float4 v = *(const float4*)&W[i];
    bf16x4 o;
    o[0] = (bf16_t)v.x; o[1] = (bf16_t)v.y; o[2] = (bf16_t)v.z; o[3] = (bf16_t)v.w;
    *(bf16x4*)&Wbf_g[i] = o;
}

// ---------------------------------------------------------------------------
// Stage 1: q = cos(x + theta) @ W^T + b  (M=16384, N=512, K=512).
// m-tile 32, full n=512 per block, grid 512. Writes qrow + per-batch
// transpose qt. Also zeroes Lacc_g.
// ---------------------------------------------------------------------------
__global__ __launch_bounds__(256, 2) void gemm_q_kernel(
    const float* __restrict__ x, const float* __restrict__ theta,
    const float* __restrict__ bias,
    bf16_t* __restrict__ qrow, bf16_t* __restrict__ qt)
{
    __shared__ alignas(16) bf16_t As[32][40];
    __shared__ alignas(16) bf16_t Ws[512][40];
    __shared__ float th[64];

    const int t    = threadIdx.x;
    const int m0   = blockIdx.x * 32;
    const int lane = t & 63;
    const int wave = t >> 6;
    const int l15  = lane & 15;
    const int quad = lane >> 4;

    if (t < 64) th[t] = theta[t];
    if (blockIdx.x < 16)
        ((float4*)Lacc_g)[blockIdx.x * 256 + t] = make_float4(0.f, 0.f, 0.f, 0.f);

    f32x4 acc[2][8];
#pragma unroll
    for (int m = 0; m < 2; ++m)
#pragma unroll
        for (int n = 0; n < 8; ++n) acc[m][n] = (f32x4){0.f, 0.f, 0.f, 0.f};

    const int arow = t >> 3;          // 0..31
    const int aseg = t & 7;           // 0..7 (4 floats)

    for (int kk = 0; kk < 16; ++kk) {
        const int k0 = kk * 32;
        __syncthreads();
        {   // A = bf16(cos(x+theta)): 32 x 32
            float4 xv = *(const float4*)&x[(m0 + arow) * 512 + k0 + aseg * 4];
            bf16x4 av;
            av[0] = (bf16_t)__cosf(xv.x + th[(k0 + aseg * 4 + 0) & 63]);
            av[1] = (bf16_t)__cosf(xv.y + th[(k0 + aseg * 4 + 1) & 63]);
            av[2] = (bf16_t)__cosf(xv.z + th[(k0 + aseg * 4 + 2) & 63]);
            av[3] = (bf16_t)__cosf(xv.w + th[(k0 + aseg * 4 + 3) & 63]);
            *(bf16x4*)&As[arow][aseg * 4] = av;
        }
        // W (already bf16): 512 rows x 32 k
#pragma unroll
        for (int cc = 0; cc < 8; ++cc) {
            int idx = t + 256 * cc;       // 0..2047
            int row = idx >> 2;           // 0..511
            int seg = idx & 3;            // 8 shorts each
            *(bf16x8*)&Ws[row][seg * 8] =
                *(const bf16x8*)&Wbf_g[row * 512 + k0 + seg * 8];
        }
        __syncthreads();
        bf16x8 af[2];
#pragma unroll
        for (int m = 0; m < 2; ++m)
            af[m] = *(const bf16x8*)&As[m * 16 + l15][quad * 8];
#pragma unroll
        for (int n = 0; n < 8; ++n) {
            bf16x8 bfr = *(const bf16x8*)&Ws[wave * 128 + n * 16 + l15][quad * 8];
#pragma unroll
            for (int m = 0; m < 2; ++m)
                acc[m][n] = __builtin_amdgcn_mfma_f32_16x16x32_bf16(af[m], bfr, acc[m][n], 0, 0, 0);
        }
    }

#pragma unroll
    for (int n = 0; n < 8; ++n) {
        const int col = wave * 128 + n * 16 + l15;
        const float bv = bias[col];
#pragma unroll
        for (int m = 0; m < 2; ++m) {
            const int row0 = m0 + m * 16 + quad * 4;
            bf16x4 pack;
#pragma unroll
            for (int r = 0; r < 4; ++r) {
                bf16_t qv = (bf16_t)(acc[m][n][r] + bv);
                qrow[(row0 + r) * 512 + col] = qv;
                pack[r] = qv;
            }
            const int b  = row0 >> 12;
            const int i0 = row0 & 4095;
            *(bf16x4*)&qt[((size_t)(b * 512 + col) << 12) + i0] = pack;
        }
    }
}

// ---------------------------------------------------------------------------
// Stage 2: attention, software-pipelined K-loop, ONE barrier per iter.
// Br=64, Bc=32, KV-split 4 -> grid 1024. Per body(it): issue DMA K(it+1)
// (double-buffered Ks), V(it-1) global loads, QK(it) = S^T via 16x16 MFMA
// (A=K from LDS, B=Q in regs -> P packs as aligned b64), exp -> Ps[it&1],
// then PV(it-1) MFMAs (A=P b128 from Ps[(it-1)&1], B=V direct from qt).
// QK work hides V-load latency; DMA waits a full body away.
// ---------------------------------------------------------------------------
__global__ __launch_bounds__(256, 2) void flash_kernel(
    const bf16_t* __restrict__ q, const bf16_t* __restrict__ qt,
    float* __restrict__ out)
{
    __shared__ alignas(16) bf16_t Ks[2][32][520];  // 66560 B (row = 1040 B)
    __shared__ alignas(16) bf16_t Ps[2][64][48];   // 12288 B (row 96 B, 16B-aligned)

    const int t    = threadIdx.x;
    const int lane = t & 63;
    const int wave = t >> 6;
    const int l15  = lane & 15;
    const int quad = lane >> 4;

    // XCD-aware remap: each XCD's resident blocks share one (batch,ksplit)
    const int L      = blockIdx.x;            // 0..1023
    const int xcd    = L & 7;
    const int slot   = L >> 3;                // 0..127
    const int g      = xcd + 8 * (slot >> 6); // 0..15
    const int qtile  = slot & 63;
    const int batch  = g >> 2;
    const int ksplit = g & 3;

    const int q0    = qtile * 64;
    const int kbase = ksplit * KT;
    const bf16_t* qb  = q  + (size_t)batch * SEQ * EMBED;
    const bf16_t* qtb = qt + (size_t)batch * EMBED * SEQ;

    // stage K(0)
#pragma unroll
    for (int cc = 0; cc < 8; ++cc) {
        const int r = cc * 4 + wave;
        async_copy16(&qb[(size_t)(kbase + r) * 512 + lane * 8], &Ks[0][r][0]);
    }

    // Q B-frags (wave owns q-rows wave*16..+15): B[n=l15][k=kf*32+quad*8+j]
    bf16x8 bQ[16];
    {
        const int row = q0 + wave * 16 + l15;
#pragma unroll
        for (int kf = 0; kf < 16; ++kf)
            bQ[kf] = *(const bf16x8*)&qb[(size_t)row * 512 + kf * 32 + quad * 8];
    }

    f32x4 O[4][8];   // PV e-split: wave owns e-range wave*128 (8 n-tiles x 16)
#pragma unroll
    for (int m = 0; m < 4; ++m)
#pragma unroll
        for (int n = 0; n < 8; ++n) O[m][n] = (f32x4){0.f, 0.f, 0.f, 0.f};
    float lpart = 0.f;

    for (int it = 0; it < FITERS; ++it) {
        const int cbuf = it & 1;
        const int pbuf = cbuf ^ 1;
        __syncthreads();   // DMA K(it) landed; Ps(it-1) visible; Ks[pbuf] reads done
        // ---- issue DMA K(it+1) into Ks[pbuf] (waited at next barrier) ----
        if (it + 1 < FITERS) {
#pragma unroll
            for (int cc = 0; cc < 8; ++cc) {
                const int r = cc * 4 + wave;
                async_copy16(&qb[(size_t)(kbase + (it + 1) * BC + r) * 512 + lane * 8],
                             &Ks[pbuf][r][0]);
            }
        }
        // ---- V(it-1) global loads (latency hidden behind QK below) ----
        bf16x8 bv[8];
        if (it) {
            const int kv = kbase + (it - 1) * BC;
#pragma unroll
            for (int n = 0; n < 8; ++n)
                bv[n] = *(const bf16x8*)&qtb[(size_t)(wave * 128 + n * 16 + l15) * 4096
                                             + kv + quad * 8];
        }
        // ---- QK(it): S^T = K * Q^T, A=K (LDS), B=Q (regs) ----
        f32x4 s[2];
#pragma unroll
        for (int kt = 0; kt < 2; ++kt) {
            f32x4 a = (f32x4){0.f, 0.f, 0.f, 0.f};
#pragma unroll
            for (int kf = 0; kf < 16; ++kf) {
                bf16x8 ak = *(const bf16x8*)&Ks[cbuf][kt * 16 + l15][kf * 32 + quad * 8];
                a = __builtin_amdgcn_mfma_f32_16x16x32_bf16(ak, bQ[kf], a, 0, 0, 0);
            }
            s[kt] = a;
        }
        // ---- P = exp(s/8): C/D col=l15=q-row, reg r = key quad*4+r ----
#pragma unroll
        for (int kt = 0; kt < 2; ++kt) {
            bf16x4 pk;
#pragma unroll
            for (int r = 0; r < 4; ++r) {
                bf16_t pb = (bf16_t)__expf(s[kt][r] * 0.125f);
                lpart += (float)pb;
                pk[r] = pb;
            }
            *(bf16x4*)&Ps[cbuf][wave * 16 + l15][kt * 16 + quad * 4] = pk;
        }
        // ---- PV(it-1): A=P from Ps[pbuf] (b128), B=bv ----
        if (it) {
            bf16x8 pa[4];
#pragma unroll
            for (int mt = 0; mt < 4; ++mt)
                pa[mt] = *(const bf16x8*)&Ps[pbuf][mt * 16 + l15][quad * 8];
#pragma unroll
            for (int n = 0; n < 8; ++n)
#pragma unroll
                for (int mt = 0; mt < 4; ++mt)
                    O[mt][n] = __builtin_amdgcn_mfma_f32_16x16x32_bf16(pa[mt], bv[n], O[mt][n], 0, 0, 0);
        }
    }
    // ---- final PV(FITERS-1) ----
    __syncthreads();
    {
        const int pbuf = (FITERS - 1) & 1;
        const int kv = kbase + (FITERS - 1) * BC;
        bf16x8 bv[8];
#pragma unroll
        for (int n = 0; n < 8; ++n)
            bv[n] = *(const bf16x8*)&qtb[(size_t)(wave * 128 + n * 16 + l15) * 4096
                                         + kv + quad * 8];
        bf16x8 pa[4];
#pragma unroll
        for (int mt = 0; mt < 4; ++mt)
            pa[mt] = *(const bf16x8*)&Ps[pbuf][mt * 16 + l15][quad * 8];
#pragma unroll
        for (int n = 0; n < 8; ++n)
#pragma unroll
            for (int mt = 0; mt < 4; ++mt)
                O[mt][n] = __builtin_amdgcn_mfma_f32_16x16x32_bf16(pa[mt], bv[n], O[mt][n], 0, 0, 0);
    }

    // ---- row exp-sums: row = wave*16+l15, keys spread over quad ----
    {
        float ls = lpart;
        ls += __shfl_xor(ls, 16);
        ls += __shfl_xor(ls, 32);
        if (quad == 0)
            atomicAdd(&Lacc_g[batch * SEQ + q0 + wave * 16 + l15], ls);
    }
    // ---- unnormalized O -> out; D: row=quad*4+r (q-row), col=l15 (e) ----
#pragma unroll
    for (int mt = 0; mt < 4; ++mt)
#pragma unroll
        for (int r = 0; r < 4; ++r) {
            const size_t row = (size_t)batch * SEQ + q0 + mt * 16 + quad * 4 + r;
#pragma unroll
            for (int n = 0; n < 8; ++n)
                atomicAdd(&out[row * 512 + wave * 128 + n * 16 + l15], O[mt][n][r]);
        }
}

// out[row][e] /= Lacc_g[row]
__global__ __launch_bounds__(256) void norm_kernel(float* __restrict__ out)
{
    const int idx = blockIdx.x * 256 + threadIdx.x;   // float4 index
    float4 v = ((float4*)out)[idx];
    const float inv = 1.0f / Lacc_g[idx >> 7];
    v.x *= inv; v.y *= inv; v.z *= inv; v.w *= inv;
    ((float4*)out)[idx] = v;
}

extern "C" void kernel_launch(void* const* d_in, const int* in_sizes, int n_in,
                              void* d_out, int out_size, void* d_ws, size_t ws_size,
                              hipStream_t stream) {
    const float* x     = (const float*)d_in[0];
    const float* theta = (const float*)d_in[1];
    const float* W     = (const float*)d_in[2];
    const float* bias  = (const float*)d_in[3];
    float* out   = (float*)d_out;
    bf16_t* qrow = (bf16_t*)d_ws;                       // [16384][512] bf16
    bf16_t* qt   = qrow + (size_t)MTOT * EMBED;         // [4][512][4096] bf16

    hipMemsetAsync(out, 0, (size_t)MTOT * EMBED * sizeof(float), stream);

    cvt_w_kernel<<<dim3(EMBED * EMBED / 4 / 256), dim3(256), 0, stream>>>(W);

    gemm_q_kernel<<<dim3(MTOT / 32), dim3(256), 0, stream>>>(x, theta, bias, qrow, qt);

    flash_kernel<<<dim3(64 * BATCH * NSPLIT), dim3(256), 0, stream>>>(qrow, qt, out);

    norm_kernel<<<dim3(MTOT * EMBED / 4 / 256), dim3(256), 0, stream>>>(out);
}